// Round 1
// baseline (212.347 us; speedup 1.0000x reference)
//
#include <hip/hip_runtime.h>
#include <hip/hip_bf16.h>

#define DD 256
#define BB 2048
#define BM 128                   // c3 rows per block tile
#define BN 64                    // batch columns per pipeline stage
#define NTILE ((DD * DD) / BM)   // 512 blocks
#define NSTAGE (BB / BN)         // 32 pipeline iterations

typedef __bf16 bf16x8 __attribute__((ext_vector_type(8)));
typedef float  f32x4  __attribute__((ext_vector_type(4)));

#define AS1 __attribute__((address_space(1)))
#define AS3 __attribute__((address_space(3)))

__device__ __forceinline__ unsigned short f2bf(float f) {
    unsigned int u = __float_as_uint(f);
    return (unsigned short)((u + 0x7FFFu + ((u >> 16) & 1u)) >> 16);  // RNE
}
__device__ __forceinline__ float bf2f(unsigned short s) {
    return __uint_as_float(((unsigned int)s) << 16);
}
__device__ __forceinline__ void async_cp16(const void* g, void* l) {
    __builtin_amdgcn_global_load_lds((const AS1 unsigned int*)g,
                                     (AS3 unsigned int*)l, 16, 0, 0);
}

// K1: fused rel = x - offsets (fp32 + bf16) and out[b] = c0 + <c1, rel_b>
__global__ void prep_all(const float* __restrict__ x, const float* __restrict__ offsets,
                         const float* __restrict__ c0, const float* __restrict__ c1,
                         float* __restrict__ rel_f32, unsigned short* __restrict__ rel_bf16,
                         float* __restrict__ out) {
    const int tid = threadIdx.x, wave = tid >> 6, lane = tid & 63;
    const float4 o4  = *(const float4*)(offsets + lane * 4);
    const float4 c14 = *(const float4*)(c1 + lane * 4);
#pragma unroll
    for (int i = 0; i < 2; ++i) {
        const int b = blockIdx.x * 8 + wave * 2 + i;
        const float4 x4 = *(const float4*)(x + (size_t)b * DD + lane * 4);
        float4 r;
        r.x = x4.x - o4.x; r.y = x4.y - o4.y; r.z = x4.z - o4.z; r.w = x4.w - o4.w;
        *(float4*)(rel_f32 + (size_t)b * DD + lane * 4) = r;
        ushort4 rb;
        rb.x = f2bf(r.x); rb.y = f2bf(r.y); rb.z = f2bf(r.z); rb.w = f2bf(r.w);
        *(ushort4*)(rel_bf16 + (size_t)b * DD + lane * 4) = rb;
        float s = r.x * c14.x + r.y * c14.y + r.z * c14.z + r.w * c14.w;
        s += __shfl_xor(s, 1);  s += __shfl_xor(s, 2);  s += __shfl_xor(s, 4);
        s += __shfl_xor(s, 8);  s += __shfl_xor(s, 16); s += __shfl_xor(s, 32);
        if (lane == 0) out[b] = c0[0] + s;
    }
}

// K3: fused GEMM (c3 tile @ rel^T) + c2 fold + weighted column reduction.
// 512 threads = 8 waves: 4 row-quarters (wm, 32 rows) x 2 k-halves (wk, 128 k).
// LDS 76 KB -> 2 blocks/CU = 16 waves/CU = 4 waves/SIMD (vs 2 before).
// __launch_bounds__(512,4) caps regs at 128: afr 32 + acc 32 + bfr 16 + misc.
// Final combine atomically adds into out (reduce_partial kernel eliminated).
__global__ __launch_bounds__(512, 4) void taylor3(
    const float* __restrict__ c3, const float* __restrict__ c2,
    const float* __restrict__ rel_f32, const unsigned short* __restrict__ rel_bf16,
    float* __restrict__ out)
{
    __shared__ unsigned short Bs[2][BN * DD];   // 64 KB, double-buffered
    __shared__ float relI[BB];                  // 8 KB: rel[:, i_t]
    __shared__ float colsum[2][8][BN];          // 4 KB, double-buffered per-wave partials

    const int tile = blockIdx.x;
    const int i_t   = tile >> 1;
    const int jbase = (tile & 1) << 7;
    const int tid  = threadIdx.x;
    const int wave = tid >> 6;
    const int lane = tid & 63;
    const int wm = wave & 3, wk = wave >> 2;
    const int lrow = lane & 15, quad = lane >> 4;

    // stage rel[:, i_t] into LDS (one-time; 4 strided reads/thread)
#pragma unroll
    for (int k = 0; k < 4; ++k) {
        const int b = tid + k * 512;
        relI[b] = rel_f32[(size_t)b * DD + i_t];
    }

    // ---- hoist c2 slice into registers (only wk==0 waves fold it) ----
    f32x4 c2a[2];
    if (wk == 0) {
#pragma unroll
        for (int mt = 0; mt < 2; ++mt) {
            const float4 t = *(const float4*)(c2 + i_t * DD + jbase + wm * 32 + mt * 16 + quad * 4);
            c2a[mt] = (f32x4){t.x, t.y, t.z, t.w};
        }
    }

    // ---- hoist A fragments: 32 rows (mt=2) x own 128-k half -> 32 VGPRs ----
    bf16x8 afr[4][2];
    {
        const float* abase = c3 + (size_t)tile * BM * DD;
#pragma unroll
        for (int mt = 0; mt < 2; ++mt) {
            const int row = wm * 32 + mt * 16 + lrow;
            const float* p = abase + (size_t)row * DD + wk * 128 + quad * 8;
#pragma unroll
            for (int ks = 0; ks < 4; ++ks) {
                float4 f0 = *(const float4*)(p + ks * 32);
                float4 f1 = *(const float4*)(p + ks * 32 + 4);
                union { unsigned short u[8]; bf16x8 v; } cv;
                cv.u[0] = f2bf(f0.x); cv.u[1] = f2bf(f0.y);
                cv.u[2] = f2bf(f0.z); cv.u[3] = f2bf(f0.w);
                cv.u[4] = f2bf(f1.x); cv.u[5] = f2bf(f1.y);
                cv.u[6] = f2bf(f1.z); cv.u[7] = f2bf(f1.w);
                afr[ks][mt] = cv.v;
            }
        }
    }

    // ---- async stage: tile nb -> Bs[buf]; 4 rounds x 16 rows, swizzled granules ----
    auto stage = [&](int nb, int buf) {
        const int b0 = nb * BN;
#pragma unroll
        for (int c = 0; c < 4; ++c) {
            const int r0 = c * 16 + wave * 2;           // wave-uniform base row
            const int row = r0 + (lane >> 5);
            const int g = (lane & 31) ^ (row & 7);      // logical granule for this phys slot
            const unsigned short* src = rel_bf16 + (size_t)(b0 + row) * DD + g * 8;
            async_cp16(src, &Bs[buf][r0 * DD]);
        }
    };

    // ---- one pipeline stage; cur is a compile-time literal at each call site ----
    auto body = [&](int nb, int cur) {
        const int b0 = nb * BN;
        __syncthreads();          // drains async loads of Bs[cur]; WAR-protects Bs[cur^1]
        if (nb + 1 < NSTAGE) stage(nb + 1, cur ^ 1);

        // combine previous stage's colsum (parity cur^1); spread over all 8 waves
        if (nb > 0 && lane < 8) {
            const int b = wave * 8 + lane;
            const int pb0 = b0 - BN;
            float v = colsum[cur ^ 1][0][b];
#pragma unroll
            for (int w = 1; w < 8; ++w) v += colsum[cur ^ 1][w][b];
            atomicAdd(out + pb0 + b, relI[pb0 + b] * v);
        }

        f32x4 acc[2][4];

        // ---- K-loop: 4 steps of 16x16x32 over this wave's 128-k half ----
        // ks = 0 peeled: MFMA writes acc from a zero C (no accvgpr zero-init)
        {
            const int glog = wk * 16 + quad;
            bf16x8 bfr[4];
#pragma unroll
            for (int nt = 0; nt < 4; ++nt) {
                const int col = nt * 16 + lrow;
                const int g = glog ^ (col & 7);
                bfr[nt] = *(const bf16x8*)(&Bs[cur][col * DD + g * 8]);
            }
            const f32x4 z4 = (f32x4){0.f, 0.f, 0.f, 0.f};
#pragma unroll
            for (int mt = 0; mt < 2; ++mt)
#pragma unroll
                for (int nt = 0; nt < 4; ++nt)
                    acc[mt][nt] = __builtin_amdgcn_mfma_f32_16x16x32_bf16(
                        afr[0][mt], bfr[nt], z4, 0, 0, 0);
        }
#pragma unroll
        for (int ks = 1; ks < 4; ++ks) {
            const int glog = wk * 16 + ks * 4 + quad;
            bf16x8 bfr[4];
#pragma unroll
            for (int nt = 0; nt < 4; ++nt) {
                const int col = nt * 16 + lrow;
                const int g = glog ^ (col & 7);
                bfr[nt] = *(const bf16x8*)(&Bs[cur][col * DD + g * 8]);
            }
#pragma unroll
            for (int mt = 0; mt < 2; ++mt)
#pragma unroll
                for (int nt = 0; nt < 4; ++nt)
                    acc[mt][nt] = __builtin_amdgcn_mfma_f32_16x16x32_bf16(
                        afr[ks][mt], bfr[nt], acc[mt][nt], 0, 0, 0);
        }

        // fold c2 once (wk==0 waves only; wk==1 epilogue is pure FMA)
        if (wk == 0) {
#pragma unroll
            for (int mt = 0; mt < 2; ++mt)
#pragma unroll
                for (int nt = 0; nt < 4; ++nt)
                    acc[mt][nt] += c2a[mt];
        }

        // ---- epilogue: s(col) = sum_rows acc * r[b, j(row)]; two indep chains ----
        float sv[4];
#pragma unroll
        for (int nt = 0; nt < 4; ++nt) {
            const int col = nt * 16 + lrow;
            float sacc[2] = {0.f, 0.f};
#pragma unroll
            for (int mt = 0; mt < 2; ++mt) {
                const int e = jbase + wm * 32 + mt * 16 + quad * 4;   // global j
                const int g = (e >> 3) ^ (col & 7);
                const ushort4 rj = *(const ushort4*)(&Bs[cur][col * DD + g * 8 + (e & 7)]);
                sacc[mt] = fmaf(acc[mt][nt][0], bf2f(rj.x), sacc[mt]);
                sacc[mt] = fmaf(acc[mt][nt][1], bf2f(rj.y), sacc[mt]);
                sacc[mt] = fmaf(acc[mt][nt][2], bf2f(rj.z), sacc[mt]);
                sacc[mt] = fmaf(acc[mt][nt][3], bf2f(rj.w), sacc[mt]);
            }
            float s = sacc[0] + sacc[1];
            s += __shfl_xor(s, 16, 64);
            s += __shfl_xor(s, 32, 64);   // all lanes hold the column total
            sv[nt] = s;
        }
        {   // lane L writes col L: sv[L>>4] (select, not dynamic index)
            const float v01 = (quad & 1) ? sv[1] : sv[0];
            const float v23 = (quad & 1) ? sv[3] : sv[2];
            colsum[cur][wave][lane] = (quad & 2) ? v23 : v01;
        }
    };

    stage(0, 0);
    for (int nb = 0; nb < NSTAGE; nb += 2) {
        body(nb, 0);
        body(nb + 1, 1);
    }

    __syncthreads();
    if (lane < 8) {   // final combine, parity (NSTAGE-1)&1 = 1
        const int b = wave * 8 + lane;
        const int pb0 = BB - BN;
        float v = colsum[1][0][b];
#pragma unroll
        for (int w = 1; w < 8; ++w) v += colsum[1][w][b];
        atomicAdd(out + pb0 + b, relI[pb0 + b] * v);
    }
}

extern "C" void kernel_launch(void* const* d_in, const int* in_sizes, int n_in,
                              void* d_out, int out_size, void* d_ws, size_t ws_size,
                              hipStream_t stream) {
    const float* x       = (const float*)d_in[0];
    const float* offsets = (const float*)d_in[1];
    const float* c0      = (const float*)d_in[2];
    const float* c1      = (const float*)d_in[3];
    const float* c2      = (const float*)d_in[4];
    const float* c3      = (const float*)d_in[5];
    float* out = (float*)d_out;

    char* ws = (char*)d_ws;
    float* rel_f32 = (float*)ws;                                             // 2 MB
    unsigned short* rel_bf16 = (unsigned short*)(ws + (size_t)BB * DD * 4);  // 1 MB

    prep_all<<<BB / 8, 256, 0, stream>>>(x, offsets, c0, c1, rel_f32, rel_bf16, out);
    taylor3<<<NTILE, 512, 0, stream>>>(c3, c2, rel_f32, rel_bf16, out);
}